// Round 1
// baseline (294.385 us; speedup 1.0000x reference)
//
#include <hip/hip_runtime.h>

#define NB   64
#define NT   256
#define NI   512
#define NO   512
#define NOBS 128
#define ETA  0.01f
#define TS   16      // timesteps staged per chunk
#define JPB  16      // rows (j) per block
#define THREADS 512  // 8 waves; each wave handles 2 rows

__global__ __launch_bounds__(THREADS, 1)
void circuit_kernel(const float* __restrict__ X,
                    const float* __restrict__ Wi,
                    const int*   __restrict__ obs,
                    float*       __restrict__ out)
{
    __shared__ float xs[TS * NI];    // 32 KB staged x
    __shared__ float ms[TS * JPB];   // 1 KB staged outputs

    const int tid  = threadIdx.x;
    const int lane = tid & 63;
    const int wv   = tid >> 6;            // wave id 0..7
    const int b    = blockIdx.x >> 3;     // 0..63
    const int jblk = blockIdx.x & 7;      // 0..7
    const int j0   = jblk * JPB + wv * 2; // first of this wave's two rows
    const int o0   = obs[j0];
    const int o1   = obs[j0 + 1];

    // Load the two observed W rows; lane owns elements i = k*64 + lane
    float w0[8], w1[8];
    const float* r0 = Wi + ((size_t)b * NO + o0) * NI;
    const float* r1 = Wi + ((size_t)b * NO + o1) * NI;
#pragma unroll
    for (int k = 0; k < 8; ++k) {
        w0[k] = r0[k * 64 + lane];
        w1[k] = r1[k * 64 + lane];
    }

    const float* xb = X + (size_t)b * NT * NI;

    for (int c = 0; c < NT / TS; ++c) {
        // ---- stage TS timesteps of x into LDS (coalesced float4) ----
        const float4* src = (const float4*)(xb + (size_t)c * TS * NI);
        float4*       dst = (float4*)xs;
#pragma unroll
        for (int p = 0; p < (TS * NI / 4) / THREADS; ++p)
            dst[p * THREADS + tid] = src[p * THREADS + tid];
        __syncthreads();

        // ---- TS recurrence steps ----
        for (int tt = 0; tt < TS; ++tt) {
            const float* xr = xs + tt * NI;
            float xv[8];
#pragma unroll
            for (int k = 0; k < 8; ++k) xv[k] = xr[k * 64 + lane];

            float s0 = 0.f, s1 = 0.f;
#pragma unroll
            for (int k = 0; k < 8; ++k) {
                s0 = fmaf(w0[k], xv[k], s0);
                s1 = fmaf(w1[k], xv[k], s1);
            }
            // wave-wide butterfly reduction (64 lanes)
#pragma unroll
            for (int off = 32; off; off >>= 1) {
                s0 += __shfl_xor(s0, off, 64);
                s1 += __shfl_xor(s1, off, 64);
            }
            const float y0 = 1.f / (1.f + __expf(-s0));
            const float y1 = 1.f / (1.f + __expf(-s1));
            if (lane == 0) {
                ms[tt * JPB + wv * 2]     = y0;
                ms[tt * JPB + wv * 2 + 1] = y1;
            }
            const float e0 = ETA * y0, e1 = ETA * y1;
#pragma unroll
            for (int k = 0; k < 8; ++k) {
                w0[k] = fmaf(e0, xv[k], w0[k]);
                w1[k] = fmaf(e1, xv[k], w1[k]);
            }
        }
        __syncthreads();

        // ---- coalesced write of this chunk's outputs ----
        if (tid < TS * JPB) {
            const int tt = tid / JPB;
            const int jj = tid % JPB;
            out[((size_t)b * NT + c * TS + tt) * NOBS + jblk * JPB + jj] =
                ms[tt * JPB + jj];
        }
    }
}

extern "C" void kernel_launch(void* const* d_in, const int* in_sizes, int n_in,
                              void* d_out, int out_size, void* d_ws, size_t ws_size,
                              hipStream_t stream)
{
    const float* X   = (const float*)d_in[0];
    const float* Wi  = (const float*)d_in[1];
    const int*   obs = (const int*)d_in[2];
    float*       out = (float*)d_out;

    hipLaunchKernelGGL(circuit_kernel, dim3(NB * 8), dim3(THREADS), 0, stream,
                       X, Wi, obs, out);
}

// Round 2
// 230.994 us; speedup vs baseline: 1.2744x; 1.2744x over previous
//
#include <hip/hip_runtime.h>

#define NB   64
#define NT   256
#define NI   512
#define NO   512
#define NOBS 128
#define ETA  0.01f
#define TS   16      // timesteps staged per chunk
#define JPB  16      // rows (j) per block
#define THREADS 512  // 8 waves; each wave handles 2 rows

// Full 64-lane sum via DPP (VALU pipe, no LDS crossbar). Result uniform (SGPR).
__device__ __forceinline__ float wave_reduce_sum(float v) {
    v += __int_as_float(__builtin_amdgcn_update_dpp(0, __float_as_int(v), 0x111, 0xf, 0xf, true)); // row_shr:1
    v += __int_as_float(__builtin_amdgcn_update_dpp(0, __float_as_int(v), 0x112, 0xf, 0xf, true)); // row_shr:2
    v += __int_as_float(__builtin_amdgcn_update_dpp(0, __float_as_int(v), 0x114, 0xf, 0xf, true)); // row_shr:4
    v += __int_as_float(__builtin_amdgcn_update_dpp(0, __float_as_int(v), 0x118, 0xf, 0xf, true)); // row_shr:8
    v += __int_as_float(__builtin_amdgcn_update_dpp(0, __float_as_int(v), 0x142, 0xa, 0xf, true)); // row_bcast:15
    v += __int_as_float(__builtin_amdgcn_update_dpp(0, __float_as_int(v), 0x143, 0xc, 0xf, true)); // row_bcast:31
    return __int_as_float(__builtin_amdgcn_readlane(__float_as_int(v), 63));
}

__global__ __launch_bounds__(THREADS, 1)
void circuit_kernel(const float* __restrict__ X,
                    const float* __restrict__ Wi,
                    const int*   __restrict__ obs,
                    float*       __restrict__ out)
{
    __shared__ float xs[TS * NI];    // 32 KB staged x
    __shared__ float ms[TS * JPB];   // 1 KB staged outputs

    const int tid  = threadIdx.x;
    const int lane = tid & 63;
    const int wv   = tid >> 6;            // wave id 0..7
    const int b    = blockIdx.x >> 3;     // 0..63
    const int jblk = blockIdx.x & 7;      // 0..7
    const int j0   = jblk * JPB + wv * 2; // first of this wave's two rows
    const int o0   = obs[j0];
    const int o1   = obs[j0 + 1];

    // Lane owns elements {lane*4+k} (k<4) and {256+lane*4+k} of each 512-row.
    const float* r0 = Wi + ((size_t)b * NO + o0) * NI;
    const float* r1 = Wi + ((size_t)b * NO + o1) * NI;
    float4 w0a = ((const float4*)r0)[lane];
    float4 w0b = ((const float4*)(r0 + 256))[lane];
    float4 w1a = ((const float4*)r1)[lane];
    float4 w1b = ((const float4*)(r1 + 256))[lane];

    const float* xb = X + (size_t)b * NT * NI;

    for (int c = 0; c < NT / TS; ++c) {
        // ---- stage TS timesteps of x into LDS (coalesced float4) ----
        const float4* src = (const float4*)(xb + (size_t)c * TS * NI);
        float4*       dst = (float4*)xs;
#pragma unroll
        for (int p = 0; p < (TS * NI / 4) / THREADS; ++p)
            dst[p * THREADS + tid] = src[p * THREADS + tid];
        __syncthreads();

        // ---- TS recurrence steps ----
        for (int tt = 0; tt < TS; ++tt) {
            const float* xr = xs + tt * NI;
            const float4 xa = *(const float4*)(xr + lane * 4);        // ds_read_b128
            const float4 xc = *(const float4*)(xr + 256 + lane * 4);  // ds_read_b128

            // dot products with 2-way partial sums for shorter dep chains
            float p0 = w0a.x * xa.x, q0 = w0a.y * xa.y;
            p0 = fmaf(w0a.z, xa.z, p0); q0 = fmaf(w0a.w, xa.w, q0);
            p0 = fmaf(w0b.x, xc.x, p0); q0 = fmaf(w0b.y, xc.y, q0);
            p0 = fmaf(w0b.z, xc.z, p0); q0 = fmaf(w0b.w, xc.w, q0);
            float p1 = w1a.x * xa.x, q1 = w1a.y * xa.y;
            p1 = fmaf(w1a.z, xa.z, p1); q1 = fmaf(w1a.w, xa.w, q1);
            p1 = fmaf(w1b.x, xc.x, p1); q1 = fmaf(w1b.y, xc.y, q1);
            p1 = fmaf(w1b.z, xc.z, p1); q1 = fmaf(w1b.w, xc.w, q1);

            const float s0 = wave_reduce_sum(p0 + q0);
            const float s1 = wave_reduce_sum(p1 + q1);

            const float y0 = __builtin_amdgcn_rcpf(1.f + __expf(-s0));
            const float y1 = __builtin_amdgcn_rcpf(1.f + __expf(-s1));
            if (lane == 0) {
                ms[tt * JPB + wv * 2]     = y0;
                ms[tt * JPB + wv * 2 + 1] = y1;
            }
            const float e0 = ETA * y0, e1 = ETA * y1;
            w0a.x = fmaf(e0, xa.x, w0a.x); w0a.y = fmaf(e0, xa.y, w0a.y);
            w0a.z = fmaf(e0, xa.z, w0a.z); w0a.w = fmaf(e0, xa.w, w0a.w);
            w0b.x = fmaf(e0, xc.x, w0b.x); w0b.y = fmaf(e0, xc.y, w0b.y);
            w0b.z = fmaf(e0, xc.z, w0b.z); w0b.w = fmaf(e0, xc.w, w0b.w);
            w1a.x = fmaf(e1, xa.x, w1a.x); w1a.y = fmaf(e1, xa.y, w1a.y);
            w1a.z = fmaf(e1, xa.z, w1a.z); w1a.w = fmaf(e1, xa.w, w1a.w);
            w1b.x = fmaf(e1, xc.x, w1b.x); w1b.y = fmaf(e1, xc.y, w1b.y);
            w1b.z = fmaf(e1, xc.z, w1b.z); w1b.w = fmaf(e1, xc.w, w1b.w);
        }
        __syncthreads();

        // ---- coalesced write of this chunk's outputs ----
        if (tid < TS * JPB) {
            const int tt = tid / JPB;
            const int jj = tid % JPB;
            out[((size_t)b * NT + c * TS + tt) * NOBS + jblk * JPB + jj] =
                ms[tt * JPB + jj];
        }
    }
}

extern "C" void kernel_launch(void* const* d_in, const int* in_sizes, int n_in,
                              void* d_out, int out_size, void* d_ws, size_t ws_size,
                              hipStream_t stream)
{
    const float* X   = (const float*)d_in[0];
    const float* Wi  = (const float*)d_in[1];
    const int*   obs = (const int*)d_in[2];
    float*       out = (float*)d_out;

    hipLaunchKernelGGL(circuit_kernel, dim3(NB * 8), dim3(THREADS), 0, stream,
                       X, Wi, obs, out);
}